// Round 5
// baseline (864.693 us; speedup 1.0000x reference)
//
#include <hip/hip_runtime.h>

#define B_  32
#define S_  1024
#define H_  1024
#define V_  50257

// instrumentation repeats (idempotent; divide top-5 dur by these)
#define REP_PRO    4
#define REP_SCORES 3
#define REP_SMCTX  8
#define REP_FC     4

typedef __attribute__((ext_vector_type(8))) short bf16x8;
typedef __attribute__((ext_vector_type(4))) float f32x4;
typedef __attribute__((ext_vector_type(8))) unsigned short u16x8;

__device__ __forceinline__ unsigned short f2b(float f) {
  union { float f; unsigned u; } v; v.f = f;
  unsigned r = 0x7FFFu + ((v.u >> 16) & 1u);
  return (unsigned short)((v.u + r) >> 16);
}
__device__ __forceinline__ float b2f(unsigned short h) {
  union { unsigned u; float f; } v; v.u = ((unsigned)h) << 16;
  return v.f;
}

__device__ __forceinline__ void async16(void* lds, const void* g) {
  typedef __attribute__((address_space(3))) void as3_void;
  typedef __attribute__((address_space(1))) void as1_void;
  as3_void* l = (as3_void*)(unsigned)(unsigned long long)lds;
  const as1_void* s = (const as1_void*)(unsigned long long)g;
  __builtin_amdgcn_global_load_lds(s, l, 16, 0, 0);
}

// ---------- fused prologue: enc conv (blocks 0..16383) + wa1 conv/part2 ----------
__global__ void prologue_kernel(const float* __restrict__ enc, unsigned short* __restrict__ enc_bf,
                                const float* __restrict__ wa1, const float* __restrict__ hidden,
                                const float* __restrict__ b_a1,
                                unsigned short* __restrict__ wa1_bf, float* __restrict__ part2) {
  __shared__ float wrow[H_];
  int tid = threadIdx.x;
  #pragma unroll 1
  for (int rep = 0; rep < REP_PRO; ++rep) {
    if (blockIdx.x < 16384) {
      size_t i = ((size_t)blockIdx.x * 256 + tid) * 8;
      float4 v0 = *(const float4*)(enc + i);
      float4 v1 = *(const float4*)(enc + i + 4);
      u16x8 o;
      o[0]=f2b(v0.x); o[1]=f2b(v0.y); o[2]=f2b(v0.z); o[3]=f2b(v0.w);
      o[4]=f2b(v1.x); o[5]=f2b(v1.y); o[6]=f2b(v1.z); o[7]=f2b(v1.w);
      *(u16x8*)(enc_bf + i) = o;
      continue;
    }
    __syncthreads();   // WAR fence on wrow across reps
    int h = blockIdx.x - 16384;
    {
      int c = tid * 4;
      float4 v = *(const float4*)(wa1 + (size_t)h * 2048 + c);
      ushort4 o;
      o.x = f2b(v.x); o.y = f2b(v.y); o.z = f2b(v.z); o.w = f2b(v.w);
      *(ushort4*)(wa1_bf + (size_t)h * 1024 + c) = o;
    }
    {
      int c = tid * 4;
      float4 v = *(const float4*)(wa1 + (size_t)h * 2048 + 1024 + c);
      wrow[c] = v.x; wrow[c+1] = v.y; wrow[c+2] = v.z; wrow[c+3] = v.w;
    }
    __syncthreads();
    int wave = tid >> 6, lane = tid & 63;
    float bias = b_a1[h];
    for (int bb = 0; bb < 8; ++bb) {
      int b = wave * 8 + bb;
      float acc = 0.f;
      for (int k = lane; k < H_; k += 64) acc += wrow[k] * hidden[b * H_ + k];
      #pragma unroll
      for (int off = 32; off; off >>= 1) acc += __shfl_xor(acc, off);
      if (lane == 0) part2[b * H_ + h] = acc + bias;
    }
  }
}

// ---------- scores GEMM: 256x256 tile, BK=64, 8-wave, 8-phase counted-vmcnt ----------
#define NT_ 16
#define BAR()  __builtin_amdgcn_s_barrier()
#define SB0()  __builtin_amdgcn_sched_barrier(0)
#define VM6()  asm volatile("s_waitcnt vmcnt(6)" ::: "memory")
#define VM0()  asm volatile("s_waitcnt vmcnt(0)" ::: "memory")

#define LOADA(MH) { _Pragma("unroll") for (int m_ = 0; m_ < 4; ++m_) \
  { _Pragma("unroll") for (int ks_ = 0; ks_ < 2; ++ks_) { \
    int lr_ = (MH)*64 + m_*16 + l15; \
    int lin_ = lr_*128 + ks_*64 + l16*16; \
    int sw_ = lin_ ^ (((lin_>>9)&1)<<5); \
    af[m_][ks_] = *(const bf16x8*)(smem + buf*32768 + wr*16384 + sw_); } } }

#define LOADB() { _Pragma("unroll") for (int n_ = 0; n_ < 4; ++n_) \
  { _Pragma("unroll") for (int ks_ = 0; ks_ < 2; ++ks_) { \
    int lr_ = (wc&1)*64 + n_*16 + l15; \
    int lin_ = lr_*128 + ks_*64 + l16*16; \
    int sw_ = lin_ ^ (((lin_>>9)&1)<<5); \
    bfr[n_][ks_] = *(const bf16x8*)(smem + 65536 + buf*32768 + (wc>>1)*16384 + sw_); } } }

#define QUAD(MH, NH) { _Pragma("unroll") for (int m_ = 0; m_ < 4; ++m_) \
  { _Pragma("unroll") for (int n_ = 0; n_ < 2; ++n_) { \
    acc[(MH)*4+m_][(NH)*2+n_] = __builtin_amdgcn_mfma_f32_16x16x32_bf16(af[m_][0], bfr[(NH)*2+n_][0], acc[(MH)*4+m_][(NH)*2+n_], 0,0,0); \
    acc[(MH)*4+m_][(NH)*2+n_] = __builtin_amdgcn_mfma_f32_16x16x32_bf16(af[m_][1], bfr[(NH)*2+n_][1], acc[(MH)*4+m_][(NH)*2+n_], 0,0,0); } } }

#define PHASES(T, DO_B1, DO_T2, VMOP) { \
  const int buf = (T) & 1; \
  LOADA(0); LOADB(); \
  if (DO_B1) stB((T)+1, 1, buf^1); \
  BAR(); SB0(); \
  __builtin_amdgcn_s_setprio(1); QUAD(0,0); __builtin_amdgcn_s_setprio(0); \
  SB0(); BAR(); \
  if (DO_T2) stB((T)+2, 0, buf); \
  BAR(); SB0(); \
  __builtin_amdgcn_s_setprio(1); QUAD(0,1); __builtin_amdgcn_s_setprio(0); \
  SB0(); BAR(); \
  LOADA(1); \
  BAR(); SB0(); \
  __builtin_amdgcn_s_setprio(1); QUAD(1,1); __builtin_amdgcn_s_setprio(0); \
  SB0(); BAR(); \
  if (DO_T2) { stA((T)+2, 0, buf); stA((T)+2, 1, buf); } \
  VMOP; \
  BAR(); SB0(); \
  __builtin_amdgcn_s_setprio(1); QUAD(1,0); __builtin_amdgcn_s_setprio(0); \
  SB0(); BAR(); }

__global__ __launch_bounds__(512, 2) void scores_gemm8(
    const unsigned short* __restrict__ A,   // enc_bf [32768][1024]
    const unsigned short* __restrict__ Bm,  // wa1_bf [1024][1024]
    const float* __restrict__ part2,        // [32][1024]
    const float* __restrict__ wa2,          // [1024]
    float* __restrict__ partials)           // [32768][16]
{
  extern __shared__ char smem[];
  const int tid = threadIdx.x;
  const int wave = tid >> 6, lane = tid & 63;
  const int wr = wave >> 2, wc = wave & 3;
  const int l15 = lane & 15, l16 = lane >> 4;
  const int bm = blockIdx.x, bn = blockIdx.y;

  const unsigned short* Abase = A  + (size_t)(bm * 256) * 1024;
  const unsigned short* Bbase = Bm + (size_t)(bn * 256) * 1024;

  const int Lc = tid * 16;
  const int Ls = Lc ^ (((Lc >> 9) & 1) << 5);
  const int sr = Ls >> 7;
  const int sk = (Ls & 127) >> 1;

  auto stA = [&](int t, int h, int db) {
    char* dst = smem + db * 32768 + h * 16384 + Lc;
    const unsigned short* src = Abase + (size_t)(h * 128 + sr) * 1024 + t * 64 + sk;
    async16(dst,        src);
    async16(dst + 8192, src + 64 * 1024);
  };
  auto stB = [&](int t, int h, int db) {
    char* dst = smem + 65536 + db * 32768 + h * 16384 + Lc;
    const unsigned short* src = Bbase + (size_t)(h * 128 + sr) * 1024 + t * 64 + sk;
    async16(dst,        src);
    async16(dst + 8192, src + 64 * 1024);
  };

  f32x4 acc[8][4];
  bf16x8 af[4][2], bfr[4][2];

  #pragma unroll 1
  for (int rep = 0; rep < REP_SCORES; ++rep) {
    #pragma unroll
    for (int i = 0; i < 8; ++i)
      #pragma unroll
      for (int j = 0; j < 4; ++j) acc[i][j] = (f32x4){0.f, 0.f, 0.f, 0.f};

    stA(0, 0, 0); stA(0, 1, 0); stB(0, 0, 0); stB(0, 1, 0);
    stB(1, 0, 1); stA(1, 0, 1); stA(1, 1, 1);
    VM6();
    BAR();

    #pragma unroll 1
    for (int t = 0; t < NT_ - 2; ++t) PHASES(t, 1, 1, VM6());
    PHASES(NT_ - 2, 1, 0, VM0());
    PHASES(NT_ - 1, 0, 0, (void)0);

    const int b = bm >> 2;
    float w2[4], p2[4];
    #pragma unroll
    for (int ni = 0; ni < 4; ++ni) {
      int col = bn * 256 + wc * 64 + ni * 16 + l15;
      w2[ni] = wa2[col];
      p2[ni] = part2[b * H_ + col];
    }
    #pragma unroll
    for (int mi = 0; mi < 8; ++mi) {
      #pragma unroll
      for (int r = 0; r < 4; ++r) {
        float s = 0.f;
        #pragma unroll
        for (int ni = 0; ni < 4; ++ni)
          s += w2[ni] * tanhf(acc[mi][ni][r] + p2[ni]);
        s += __shfl_xor(s, 1); s += __shfl_xor(s, 2);
        s += __shfl_xor(s, 4); s += __shfl_xor(s, 8);
        if (l15 == 0) {
          int row = bm * 256 + wr * 128 + mi * 16 + l16 * 4 + r;
          partials[(size_t)row * 16 + bn * 4 + wc] = s;
        }
      }
    }
  }
}

// ---------- fused softmax + context chunk: block (sc, b) ----------
__global__ __launch_bounds__(256) void smctx_kernel(
    const float* __restrict__ partials, const unsigned short* __restrict__ encbf,
    float* __restrict__ ctxp) {
  int sc = blockIdx.x, b = blockIdx.y, tid = threadIdx.x;
  int lane = tid & 63, wid = tid >> 6;
  __shared__ float att[1024];
  __shared__ float red[4];
  #pragma unroll 1
  for (int rep = 0; rep < REP_SMCTX; ++rep) {
    __syncthreads();   // WAR fence on att/red across reps
    float scv[4];
    float mx = -1e30f;
    #pragma unroll
    for (int j = 0; j < 4; ++j) {
      int r = tid * 4 + j;
      const float4* p = (const float4*)(partials + ((size_t)b * 1024 + r) * 16);
      float s = 0.f;
      #pragma unroll
      for (int i = 0; i < 4; ++i) { float4 v = p[i]; s += v.x + v.y + v.z + v.w; }
      scv[j] = s; mx = fmaxf(mx, s);
    }
    #pragma unroll
    for (int off = 32; off; off >>= 1) mx = fmaxf(mx, __shfl_xor(mx, off));
    if (lane == 0) red[wid] = mx;
    __syncthreads();
    float M = fmaxf(fmaxf(red[0], red[1]), fmaxf(red[2], red[3]));
    float ssum = 0.f;
    #pragma unroll
    for (int j = 0; j < 4; ++j) { float e = expf(scv[j] - M); att[tid*4+j] = e; ssum += e; }
    #pragma unroll
    for (int off = 32; off; off >>= 1) ssum += __shfl_xor(ssum, off);
    __syncthreads();
    if (lane == 0) red[wid] = ssum;
    __syncthreads();
    float inv = 1.f / (red[0] + red[1] + red[2] + red[3]);
    int h4 = tid * 4;
    float a0 = 0, a1 = 0, a2 = 0, a3 = 0;
    const unsigned short* base = encbf + (size_t)b * S_ * H_ + h4;
    #pragma unroll 4
    for (int i = 0; i < 64; ++i) {
      float w = att[sc * 64 + i] * inv;
      ushort4 ev = *(const ushort4*)(base + (size_t)(sc * 64 + i) * H_);
      a0 += w * b2f(ev.x); a1 += w * b2f(ev.y); a2 += w * b2f(ev.z); a3 += w * b2f(ev.w);
    }
    float4 o = {a0, a1, a2, a3};
    *(float4*)(ctxp + (size_t)(sc * B_ + b) * H_ + h4) = o;
  }
}

// ---------- W_c GEMM with inline ec construction: block (nb, kc) ----------
__global__ __launch_bounds__(256) void wc_gemm(
    const int* __restrict__ word, const float* __restrict__ emb,
    const float* __restrict__ ctxp, const float* __restrict__ Wc,
    float* __restrict__ xp) {
  int nb = blockIdx.x, kc = blockIdx.y, tid = threadIdx.x;
  __shared__ unsigned short A_lds[32][136];
  {
    int b = tid >> 3, cg = tid & 7;
    int c0 = cg * 16;
    if (kc < 8) {
      int w = word[b];
      const float* er = emb + (size_t)w * H_ + kc * 128 + c0;
      #pragma unroll
      for (int c = 0; c < 16; c += 4) {
        float4 v = *(const float4*)(er + c);
        ushort4 o; o.x = f2b(v.x); o.y = f2b(v.y); o.z = f2b(v.z); o.w = f2b(v.w);
        *(ushort4*)&A_lds[b][c0 + c] = o;
      }
    } else {
      int h0 = (kc - 8) * 128 + c0;
      #pragma unroll
      for (int c = 0; c < 16; c += 4) {
        float s0 = 0, s1 = 0, s2 = 0, s3 = 0;
        #pragma unroll
        for (int sc = 0; sc < 16; ++sc) {
          float4 v = *(const float4*)(ctxp + ((size_t)(sc * B_ + b)) * H_ + h0 + c);
          s0 += v.x; s1 += v.y; s2 += v.z; s3 += v.w;
        }
        ushort4 o; o.x = f2b(s0); o.y = f2b(s1); o.z = f2b(s2); o.w = f2b(s3);
        *(ushort4*)&A_lds[b][c0 + c] = o;
      }
    }
  }
  __syncthreads();
  int wave = tid >> 6, lane = tid & 63, l15 = lane & 15, l16 = lane >> 4;
  int col = nb * 64 + wave * 16 + l15;
  const float* bp = Wc + (size_t)col * 2048 + kc * 128 + l16 * 8;
  f32x4 acc0 = {0.f,0.f,0.f,0.f}, acc1 = {0.f,0.f,0.f,0.f};
  #pragma unroll
  for (int k = 0; k < 128; k += 32) {
    bf16x8 a0 = *(const bf16x8*)&A_lds[l15][k + l16 * 8];
    bf16x8 a1 = *(const bf16x8*)&A_lds[16 + l15][k + l16 * 8];
    float4 bv0 = *(const float4*)(bp + k);
    float4 bv1 = *(const float4*)(bp + k + 4);
    bf16x8 bb;
    bb[0] = (short)f2b(bv0.x); bb[1] = (short)f2b(bv0.y);
    bb[2] = (short)f2b(bv0.z); bb[3] = (short)f2b(bv0.w);
    bb[4] = (short)f2b(bv1.x); bb[5] = (short)f2b(bv1.y);
    bb[6] = (short)f2b(bv1.z); bb[7] = (short)f2b(bv1.w);
    acc0 = __builtin_amdgcn_mfma_f32_16x16x32_bf16(a0, bb, acc0, 0, 0, 0);
    acc1 = __builtin_amdgcn_mfma_f32_16x16x32_bf16(a1, bb, acc1, 0, 0, 0);
  }
  #pragma unroll
  for (int r = 0; r < 4; ++r) {
    int m = l16 * 4 + r;
    xp[(size_t)(kc * 32 + m) * H_ + col] = acc0[r];
    xp[(size_t)(kc * 32 + 16 + m) * H_ + col] = acc1[r];
  }
}

// ---------- fused W_ih / W_hh GEMM with inline x / hprev construction ----------
__global__ __launch_bounds__(256) void ihhh_gemm(
    const float* __restrict__ xp, const float* __restrict__ b_c,
    const float* __restrict__ hidden,
    const float* __restrict__ W_ih, const float* __restrict__ W_hh,
    float* __restrict__ gip, float* __restrict__ ghp) {
  int nb = blockIdx.x, kc = blockIdx.y, z = blockIdx.z, tid = threadIdx.x;
  __shared__ unsigned short A_lds[32][136];
  {
    int b = tid >> 3, cg = tid & 7;
    int c0 = cg * 16;
    int h0 = kc * 128 + c0;
    if (z == 0) {
      #pragma unroll
      for (int c = 0; c < 16; c += 4) {
        float4 bias = *(const float4*)(b_c + h0 + c);
        float s0 = bias.x, s1 = bias.y, s2 = bias.z, s3 = bias.w;
        #pragma unroll
        for (int sc = 0; sc < 16; ++sc) {
          float4 v = *(const float4*)(xp + ((size_t)(sc * B_ + b)) * H_ + h0 + c);
          s0 += v.x; s1 += v.y; s2 += v.z; s3 += v.w;
        }
        ushort4 o;
        o.x = f2b(fmaxf(s0, 0.f)); o.y = f2b(fmaxf(s1, 0.f));
        o.z = f2b(fmaxf(s2, 0.f)); o.w = f2b(fmaxf(s3, 0.f));
        *(ushort4*)&A_lds[b][c0 + c] = o;
      }
    } else {
      #pragma unroll
      for (int c = 0; c < 16; c += 4) {
        float4 v = *(const float4*)(hidden + (size_t)b * H_ + h0 + c);
        ushort4 o; o.x = f2b(v.x); o.y = f2b(v.y); o.z = f2b(v.z); o.w = f2b(v.w);
        *(ushort4*)&A_lds[b][c0 + c] = o;
      }
    }
  }
  __syncthreads();
  const float* Bw = z ? W_hh : W_ih;
  float* C = z ? ghp : gip;
  int wave = tid >> 6, lane = tid & 63, l15 = lane & 15, l16 = lane >> 4;
  int col = nb * 64 + wave * 16 + l15;
  const float* bp = Bw + (size_t)col * 1024 + kc * 128 + l16 * 8;
  f32x4 acc0 = {0.f,0.f,0.f,0.f}, acc1 = {0.f,0.f,0.f,0.f};
  #pragma unroll
  for (int k = 0; k < 128; k += 32) {
    bf16x8 a0 = *(const bf16x8*)&A_lds[l15][k + l16 * 8];
    bf16x8 a1 = *(const bf16x8*)&A_lds[16 + l15][k + l16 * 8];
    float4 bv0 = *(const float4*)(bp + k);
    float4 bv1 = *(const float4*)(bp + k + 4);
    bf16x8 bb;
    bb[0] = (short)f2b(bv0.x); bb[1] = (short)f2b(bv0.y);
    bb[2] = (short)f2b(bv0.z); bb[3] = (short)f2b(bv0.w);
    bb[4] = (short)f2b(bv1.x); bb[5] = (short)f2b(bv1.y);
    bb[6] = (short)f2b(bv1.z); bb[7] = (short)f2b(bv1.w);
    acc0 = __builtin_amdgcn_mfma_f32_16x16x32_bf16(a0, bb, acc0, 0, 0, 0);
    acc1 = __builtin_amdgcn_mfma_f32_16x16x32_bf16(a1, bb, acc1, 0, 0, 0);
  }
  #pragma unroll
  for (int r = 0; r < 4; ++r) {
    int m = l16 * 4 + r;
    C[(size_t)(kc * 32 + m) * 3072 + col] = acc0[r];
    C[(size_t)(kc * 32 + 16 + m) * 3072 + col] = acc1[r];
  }
}

// ---------- GRU gates + h_new (8 chunks) ----------
__global__ void gates_kernel(const float* __restrict__ gip, const float* __restrict__ ghp,
                             const float* __restrict__ b_ih, const float* __restrict__ b_hh,
                             const float* __restrict__ hidden, float* __restrict__ hnew_out,
                             unsigned short* __restrict__ hr_bf) {
  int i = blockIdx.x * 256 + threadIdx.x;   // 32768
  int b = i >> 10, h = i & 1023;
  float g[6];
  #pragma unroll
  for (int t = 0; t < 3; ++t) {
    int j = h + t * H_;
    float vi = b_ih[j], vh = b_hh[j];
    #pragma unroll
    for (int kc = 0; kc < 8; ++kc) {
      vi += gip[(size_t)(kc * B_ + b) * 3072 + j];
      vh += ghp[(size_t)(kc * B_ + b) * 3072 + j];
    }
    g[t] = vi; g[3 + t] = vh;
  }
  float r = 1.f / (1.f + expf(-(g[0] + g[3])));
  float z = 1.f / (1.f + expf(-(g[1] + g[4])));
  float n = tanhf(g[2] + r * g[5]);
  float hv = (1.f - z) * n + z * hidden[i];
  hnew_out[i] = hv;
  hr_bf[i] = f2b(hv > 0.f ? hv : 0.f);
}

// ---------- final skinny GEMM: out[32,V] = hr_bf @ W_fc^T + b_fc ----------
__global__ __launch_bounds__(256) void fc_gemm(
    const unsigned short* __restrict__ A, const float* __restrict__ Bw,
    float* __restrict__ C, const float* __restrict__ bias) {
  const int N = V_, K = 1024;
  int n0 = blockIdx.x * 64;
  int wave = threadIdx.x >> 6, lane = threadIdx.x & 63;
  int l15 = lane & 15, l16 = lane >> 4;
  int col = n0 + wave * 16 + l15;
  int vclamp = col < N ? col : N - 1;
  const unsigned short* a0p = A + l15 * K + l16 * 8;
  const unsigned short* a1p = A + (16 + l15) * K + l16 * 8;
  const float* bp = Bw + (size_t)vclamp * K + l16 * 8;
  #pragma unroll 1
  for (int rep = 0; rep < REP_FC; ++rep) {
    f32x4 acc0 = {0.f,0.f,0.f,0.f}, acc1 = {0.f,0.f,0.f,0.f};
    #pragma unroll 4
    for (int k = 0; k < K; k += 32) {
      bf16x8 a0 = *(const bf16x8*)(a0p + k);
      bf16x8 a1 = *(const bf16x8*)(a1p + k);
      float4 bv0 = *(const float4*)(bp + k);
      float4 bv1 = *(const float4*)(bp + k + 4);
      bf16x8 bb;
      bb[0] = (short)f2b(bv0.x); bb[1] = (short)f2b(bv0.y);
      bb[2] = (short)f2b(bv0.z); bb[3] = (short)f2b(bv0.w);
      bb[4] = (short)f2b(bv1.x); bb[5] = (short)f2b(bv1.y);
      bb[6] = (short)f2b(bv1.z); bb[7] = (short)f2b(bv1.w);
      acc0 = __builtin_amdgcn_mfma_f32_16x16x32_bf16(a0, bb, acc0, 0, 0, 0);
      acc1 = __builtin_amdgcn_mfma_f32_16x16x32_bf16(a1, bb, acc1, 0, 0, 0);
    }
    if (col < N) {
      float bv = bias[col];
      #pragma unroll
      for (int r = 0; r < 4; ++r) {
        int m = l16 * 4 + r;
        C[(size_t)m * N + col] = acc0[r] + bv;
        C[(size_t)(16 + m) * N + col] = acc1[r] + bv;
      }
    }
  }
}

extern "C" void kernel_launch(void* const* d_in, const int* in_sizes, int n_in,
                              void* d_out, int out_size, void* d_ws, size_t ws_size,
                              hipStream_t stream) {
  const int*   word   = (const int*)  d_in[0];
  const float* hidden = (const float*)d_in[1];
  const float* enc    = (const float*)d_in[2];
  const float* emb    = (const float*)d_in[3];
  const float* W_a1   = (const float*)d_in[4];
  const float* b_a1   = (const float*)d_in[5];
  const float* W_a2   = (const float*)d_in[6];
  const float* b_c    = (const float*)d_in[9];
  const float* W_c    = (const float*)d_in[8];
  const float* W_ih   = (const float*)d_in[10];
  const float* W_hh   = (const float*)d_in[11];
  const float* b_ih   = (const float*)d_in[12];
  const float* b_hh   = (const float*)d_in[13];
  const float* W_fc   = (const float*)d_in[14];
  const float* b_fc   = (const float*)d_in[15];
  float* out = (float*)d_out;

  if (ws_size < 73596928ull) return;  // loud failure

  char* ws = (char*)d_ws;
  unsigned short* enc_bf   = (unsigned short*)(ws + 0);
  float*          gip      = (float*)         (ws + 0);
  float*          ghp      = (float*)         (ws + 3145728);
  unsigned short* wa1_bf   = (unsigned short*)(ws + 67108864);
  float*          xp       = (float*)         (ws + 67108864);
  float*          part2    = (float*)         (ws + 69206016);
  float*          partials = (float*)         (ws + 69337088);
  float*          ctxp     = (float*)         (ws + 71434240);
  unsigned short* hr_bf    = (unsigned short*)(ws + 73531392);

  hipFuncSetAttribute((const void*)scores_gemm8,
                      hipFuncAttributeMaxDynamicSharedMemorySize, 131072);

  prologue_kernel<<<dim3(17408), dim3(256), 0, stream>>>(enc, enc_bf, W_a1, hidden, b_a1,
                                                         wa1_bf, part2);
  scores_gemm8<<<dim3(128, 4), dim3(512), 131072, stream>>>(enc_bf, wa1_bf, part2, W_a2, partials);
  smctx_kernel<<<dim3(16, 32), dim3(256), 0, stream>>>(partials, enc_bf, ctxp);
  wc_gemm<<<dim3(16, 16), dim3(256), 0, stream>>>(word, emb, ctxp, W_c, xp);
  ihhh_gemm<<<dim3(48, 8, 2), dim3(256), 0, stream>>>(xp, b_c, hidden, W_ih, W_hh, gip, ghp);
  gates_kernel<<<dim3(128), dim3(256), 0, stream>>>(gip, ghp, b_ih, b_hh, hidden,
                                                    out + (size_t)B_ * V_, hr_bf);
  fc_gemm<<<dim3(786), dim3(256), 0, stream>>>(hr_bf, W_fc, out, b_fc);
}

// Round 6
// 285.230 us; speedup vs baseline: 3.0316x; 3.0316x over previous
//
#include <hip/hip_runtime.h>

#define B_  32
#define S_  1024
#define H_  1024
#define V_  50257

typedef __attribute__((ext_vector_type(8))) short bf16x8;
typedef __attribute__((ext_vector_type(4))) float f32x4;
typedef __attribute__((ext_vector_type(8))) unsigned short u16x8;

__device__ __forceinline__ unsigned short f2b(float f) {
  union { float f; unsigned u; } v; v.f = f;
  unsigned r = 0x7FFFu + ((v.u >> 16) & 1u);
  return (unsigned short)((v.u + r) >> 16);
}
__device__ __forceinline__ float b2f(unsigned short h) {
  union { unsigned u; float f; } v; v.u = ((unsigned)h) << 16;
  return v.f;
}

__device__ __forceinline__ void async16(void* lds, const void* g) {
  typedef __attribute__((address_space(3))) void as3_void;
  typedef __attribute__((address_space(1))) void as1_void;
  as3_void* l = (as3_void*)(unsigned)(unsigned long long)lds;
  const as1_void* s = (const as1_void*)(unsigned long long)g;
  __builtin_amdgcn_global_load_lds(s, l, 16, 0, 0);
}

// ---------- fused prologue: enc conv (blocks 0..16383) + wa1 conv/part2 ----------
__global__ void prologue_kernel(const float* __restrict__ enc, unsigned short* __restrict__ enc_bf,
                                const float* __restrict__ wa1, const float* __restrict__ hidden,
                                const float* __restrict__ b_a1,
                                unsigned short* __restrict__ wa1_bf, float* __restrict__ part2) {
  __shared__ float wrow[H_];
  int tid = threadIdx.x;
  if (blockIdx.x < 16384) {
    size_t i = ((size_t)blockIdx.x * 256 + tid) * 8;
    float4 v0 = *(const float4*)(enc + i);
    float4 v1 = *(const float4*)(enc + i + 4);
    u16x8 o;
    o[0]=f2b(v0.x); o[1]=f2b(v0.y); o[2]=f2b(v0.z); o[3]=f2b(v0.w);
    o[4]=f2b(v1.x); o[5]=f2b(v1.y); o[6]=f2b(v1.z); o[7]=f2b(v1.w);
    *(u16x8*)(enc_bf + i) = o;
    return;
  }
  int h = blockIdx.x - 16384;
  {
    int c = tid * 4;
    float4 v = *(const float4*)(wa1 + (size_t)h * 2048 + c);
    ushort4 o;
    o.x = f2b(v.x); o.y = f2b(v.y); o.z = f2b(v.z); o.w = f2b(v.w);
    *(ushort4*)(wa1_bf + (size_t)h * 1024 + c) = o;
  }
  {
    int c = tid * 4;
    float4 v = *(const float4*)(wa1 + (size_t)h * 2048 + 1024 + c);
    wrow[c] = v.x; wrow[c+1] = v.y; wrow[c+2] = v.z; wrow[c+3] = v.w;
  }
  __syncthreads();
  int wave = tid >> 6, lane = tid & 63;
  float bias = b_a1[h];
  for (int bb = 0; bb < 8; ++bb) {
    int b = wave * 8 + bb;
    float acc = 0.f;
    for (int k = lane; k < H_; k += 64) acc += wrow[k] * hidden[b * H_ + k];
    #pragma unroll
    for (int off = 32; off; off >>= 1) acc += __shfl_xor(acc, off);
    if (lane == 0) part2[b * H_ + h] = acc + bias;
  }
}

// ---------- scores GEMM: 256x256 tile, BK=64, 8-wave, 8-phase counted-vmcnt ----------
// LDS (dynamic 128KB): A [0,65536), B [65536,131072); per 16KB half-tile:
//   linear byte L = row*128 + colbyte (row 0..127, 64 bf16 cols)
//   physical byte P = L ^ ((row&7)<<4)   (row = L>>7 = P>>7; self-inverse)
// -> 16 fragment rows spread over all 8 bank-quads (2 lanes/bank = free, m136).
// Stage: linear LDS dest P, source col pre-swizzled: (P&127) ^ ((row&7)<<4)  [rule #21]
#define NT_ 16
#define BAR()  __builtin_amdgcn_s_barrier()
#define SB0()  __builtin_amdgcn_sched_barrier(0)
#define VM6()  asm volatile("s_waitcnt vmcnt(6)" ::: "memory")
#define VM0()  asm volatile("s_waitcnt vmcnt(0)" ::: "memory")

#define LOADA(MH) { _Pragma("unroll") for (int m_ = 0; m_ < 4; ++m_) \
  { _Pragma("unroll") for (int ks_ = 0; ks_ < 2; ++ks_) { \
    int lr_ = (MH)*64 + m_*16 + l15; \
    int lin_ = lr_*128 + ks_*64 + l16*16; \
    int sw_ = lin_ ^ ((lr_ & 7) << 4); \
    af[m_][ks_] = *(const bf16x8*)(smem + buf*32768 + wr*16384 + sw_); } } }

#define LOADB() { _Pragma("unroll") for (int n_ = 0; n_ < 4; ++n_) \
  { _Pragma("unroll") for (int ks_ = 0; ks_ < 2; ++ks_) { \
    int lr_ = (wc&1)*64 + n_*16 + l15; \
    int lin_ = lr_*128 + ks_*64 + l16*16; \
    int sw_ = lin_ ^ ((lr_ & 7) << 4); \
    bfr[n_][ks_] = *(const bf16x8*)(smem + 65536 + buf*32768 + (wc>>1)*16384 + sw_); } } }

#define QUAD(MH, NH) { _Pragma("unroll") for (int m_ = 0; m_ < 4; ++m_) \
  { _Pragma("unroll") for (int n_ = 0; n_ < 2; ++n_) { \
    acc[(MH)*4+m_][(NH)*2+n_] = __builtin_amdgcn_mfma_f32_16x16x32_bf16(af[m_][0], bfr[(NH)*2+n_][0], acc[(MH)*4+m_][(NH)*2+n_], 0,0,0); \
    acc[(MH)*4+m_][(NH)*2+n_] = __builtin_amdgcn_mfma_f32_16x16x32_bf16(af[m_][1], bfr[(NH)*2+n_][1], acc[(MH)*4+m_][(NH)*2+n_], 0,0,0); } } }

#define PHASES(T, DO_B1, DO_T2, VMOP) { \
  const int buf = (T) & 1; \
  LOADA(0); LOADB(); \
  if (DO_B1) stB((T)+1, 1, buf^1); \
  BAR(); SB0(); \
  __builtin_amdgcn_s_setprio(1); QUAD(0,0); __builtin_amdgcn_s_setprio(0); \
  SB0(); BAR(); \
  if (DO_T2) stB((T)+2, 0, buf); \
  BAR(); SB0(); \
  __builtin_amdgcn_s_setprio(1); QUAD(0,1); __builtin_amdgcn_s_setprio(0); \
  SB0(); BAR(); \
  LOADA(1); \
  BAR(); SB0(); \
  __builtin_amdgcn_s_setprio(1); QUAD(1,1); __builtin_amdgcn_s_setprio(0); \
  SB0(); BAR(); \
  if (DO_T2) { stA((T)+2, 0, buf); stA((T)+2, 1, buf); } \
  VMOP; \
  BAR(); SB0(); \
  __builtin_amdgcn_s_setprio(1); QUAD(1,0); __builtin_amdgcn_s_setprio(0); \
  SB0(); BAR(); }

__global__ __launch_bounds__(512, 2) void scores_gemm8(
    const unsigned short* __restrict__ A,   // enc_bf [32768][1024]
    const unsigned short* __restrict__ Bm,  // wa1_bf [1024][1024]
    const float* __restrict__ part2,        // [32][1024]
    const float* __restrict__ wa2,          // [1024]
    float* __restrict__ partials)           // [32768][16]
{
  extern __shared__ char smem[];
  const int tid = threadIdx.x;
  const int wave = tid >> 6, lane = tid & 63;
  const int wr = wave >> 2, wc = wave & 3;
  const int l15 = lane & 15, l16 = lane >> 4;
  const int bm = blockIdx.x, bn = blockIdx.y;

  const unsigned short* Abase = A  + (size_t)(bm * 256) * 1024;
  const unsigned short* Bbase = Bm + (size_t)(bn * 256) * 1024;

  // staging: thread tid covers physical granules P=tid*16 (rows 0..63) and P+8192 (rows 64..127)
  const int Lc = tid * 16;
  const int sr = Lc >> 7;                              // row 0..63
  const int skb = (Lc & 127) ^ ((sr & 7) << 4);        // inverse-swizzled source col (bytes)
  const int sk = skb >> 1;                             // bf16 elements

  auto stA = [&](int t, int h, int db) {
    char* dst = smem + db * 32768 + h * 16384 + Lc;
    const unsigned short* src = Abase + (size_t)(h * 128 + sr) * 1024 + t * 64 + sk;
    async16(dst,        src);
    async16(dst + 8192, src + 64 * 1024);   // row+64: (row&7) unchanged -> same skb
  };
  auto stB = [&](int t, int h, int db) {
    char* dst = smem + 65536 + db * 32768 + h * 16384 + Lc;
    const unsigned short* src = Bbase + (size_t)(h * 128 + sr) * 1024 + t * 64 + sk;
    async16(dst,        src);
    async16(dst + 8192, src + 64 * 1024);
  };

  f32x4 acc[8][4];
  #pragma unroll
  for (int i = 0; i < 8; ++i)
    #pragma unroll
    for (int j = 0; j < 4; ++j) acc[i][j] = (f32x4){0.f, 0.f, 0.f, 0.f};
  bf16x8 af[4][2], bfr[4][2];

  // prologue: tile0 all 4 halves, tile1 {B0, A0, A1}; leaves 3 half-tiles in flight
  stA(0, 0, 0); stA(0, 1, 0); stB(0, 0, 0); stB(0, 1, 0);
  stB(1, 0, 1); stA(1, 0, 1); stA(1, 1, 1);
  VM6();
  BAR();

  #pragma unroll 1
  for (int t = 0; t < NT_ - 2; ++t) PHASES(t, 1, 1, VM6());
  PHASES(NT_ - 2, 1, 0, VM0());
  PHASES(NT_ - 1, 0, 0, (void)0);

  // fused epilogue: partials[row][bn*4+wc] = sum over 64-col group of wa2*tanh(acc+part2)
  const int b = bm >> 2;
  float w2[4], p2[4];
  #pragma unroll
  for (int ni = 0; ni < 4; ++ni) {
    int col = bn * 256 + wc * 64 + ni * 16 + l15;
    w2[ni] = wa2[col];
    p2[ni] = part2[b * H_ + col];
  }
  #pragma unroll
  for (int mi = 0; mi < 8; ++mi) {
    #pragma unroll
    for (int r = 0; r < 4; ++r) {
      float s = 0.f;
      #pragma unroll
      for (int ni = 0; ni < 4; ++ni)
        s += w2[ni] * tanhf(acc[mi][ni][r] + p2[ni]);
      s += __shfl_xor(s, 1); s += __shfl_xor(s, 2);
      s += __shfl_xor(s, 4); s += __shfl_xor(s, 8);
      if (l15 == 0) {
        int row = bm * 256 + wr * 128 + mi * 16 + l16 * 4 + r;
        partials[(size_t)row * 16 + bn * 4 + wc] = s;
      }
    }
  }
}

// ---------- fused softmax + context chunk: block (sc, b) ----------
__global__ __launch_bounds__(256) void smctx_kernel(
    const float* __restrict__ partials, const unsigned short* __restrict__ encbf,
    float* __restrict__ ctxp) {
  int sc = blockIdx.x, b = blockIdx.y, tid = threadIdx.x;
  int lane = tid & 63, wid = tid >> 6;
  __shared__ float att[1024];
  __shared__ float red[4];
  float scv[4];
  float mx = -1e30f;
  #pragma unroll
  for (int j = 0; j < 4; ++j) {
    int r = tid * 4 + j;
    const float4* p = (const float4*)(partials + ((size_t)b * 1024 + r) * 16);
    float s = 0.f;
    #pragma unroll
    for (int i = 0; i < 4; ++i) { float4 v = p[i]; s += v.x + v.y + v.z + v.w; }
    scv[j] = s; mx = fmaxf(mx, s);
  }
  #pragma unroll
  for (int off = 32; off; off >>= 1) mx = fmaxf(mx, __shfl_xor(mx, off));
  if (lane == 0) red[wid] = mx;
  __syncthreads();
  float M = fmaxf(fmaxf(red[0], red[1]), fmaxf(red[2], red[3]));
  float ssum = 0.f;
  #pragma unroll
  for (int j = 0; j < 4; ++j) { float e = expf(scv[j] - M); att[tid*4+j] = e; ssum += e; }
  #pragma unroll
  for (int off = 32; off; off >>= 1) ssum += __shfl_xor(ssum, off);
  __syncthreads();
  if (lane == 0) red[wid] = ssum;
  __syncthreads();
  float inv = 1.f / (red[0] + red[1] + red[2] + red[3]);
  int h4 = tid * 4;
  float a0 = 0, a1 = 0, a2 = 0, a3 = 0;
  const unsigned short* base = encbf + (size_t)b * S_ * H_ + h4;
  #pragma unroll 4
  for (int i = 0; i < 64; ++i) {
    float w = att[sc * 64 + i] * inv;
    ushort4 ev = *(const ushort4*)(base + (size_t)(sc * 64 + i) * H_);
    a0 += w * b2f(ev.x); a1 += w * b2f(ev.y); a2 += w * b2f(ev.z); a3 += w * b2f(ev.w);
  }
  float4 o = {a0, a1, a2, a3};
  *(float4*)(ctxp + (size_t)(sc * B_ + b) * H_ + h4) = o;
}

// ---------- W_c GEMM with inline ec construction: block (nb, kc) ----------
__global__ __launch_bounds__(256) void wc_gemm(
    const int* __restrict__ word, const float* __restrict__ emb,
    const float* __restrict__ ctxp, const float* __restrict__ Wc,
    float* __restrict__ xp) {
  int nb = blockIdx.x, kc = blockIdx.y, tid = threadIdx.x;
  __shared__ unsigned short A_lds[32][136];
  {
    int b = tid >> 3, cg = tid & 7;
    int c0 = cg * 16;
    if (kc < 8) {
      int w = word[b];
      const float* er = emb + (size_t)w * H_ + kc * 128 + c0;
      #pragma unroll
      for (int c = 0; c < 16; c += 4) {
        float4 v = *(const float4*)(er + c);
        ushort4 o; o.x = f2b(v.x); o.y = f2b(v.y); o.z = f2b(v.z); o.w = f2b(v.w);
        *(ushort4*)&A_lds[b][c0 + c] = o;
      }
    } else {
      int h0 = (kc - 8) * 128 + c0;
      #pragma unroll
      for (int c = 0; c < 16; c += 4) {
        float s0 = 0, s1 = 0, s2 = 0, s3 = 0;
        #pragma unroll
        for (int sc = 0; sc < 16; ++sc) {
          float4 v = *(const float4*)(ctxp + ((size_t)(sc * B_ + b)) * H_ + h0 + c);
          s0 += v.x; s1 += v.y; s2 += v.z; s3 += v.w;
        }
        ushort4 o; o.x = f2b(s0); o.y = f2b(s1); o.z = f2b(s2); o.w = f2b(s3);
        *(ushort4*)&A_lds[b][c0 + c] = o;
      }
    }
  }
  __syncthreads();
  int wave = tid >> 6, lane = tid & 63, l15 = lane & 15, l16 = lane >> 4;
  int col = nb * 64 + wave * 16 + l15;
  const float* bp = Wc + (size_t)col * 2048 + kc * 128 + l16 * 8;
  f32x4 acc0 = {0.f,0.f,0.f,0.f}, acc1 = {0.f,0.f,0.f,0.f};
  #pragma unroll
  for (int k = 0; k < 128; k += 32) {
    bf16x8 a0 = *(const bf16x8*)&A_lds[l15][k + l16 * 8];
    bf16x8 a1 = *(const bf16x8*)&A_lds[16 + l15][k + l16 * 8];
    float4 bv0 = *(const float4*)(bp + k);
    float4 bv1 = *(const float4*)(bp + k + 4);
    bf16x8 bb;
    bb[0] = (short)f2b(bv0.x); bb[1] = (short)f2b(bv0.y);
    bb[2] = (short)f2b(bv0.z); bb[3] = (short)f2b(bv0.w);
    bb[4] = (short)f2b(bv1.x); bb[5] = (short)f2b(bv1.y);
    bb[6] = (short)f2b(bv1.z); bb[7] = (short)f2b(bv1.w);
    acc0 = __builtin_amdgcn_mfma_f32_16x16x32_bf16(a0, bb, acc0, 0, 0, 0);
    acc1 = __builtin_amdgcn_mfma_f32_16x16x32_bf16(a1, bb, acc1, 0, 0, 0);
  }
  #pragma unroll
  for (int r = 0; r < 4; ++r) {
    int m = l16 * 4 + r;
    xp[(size_t)(kc * 32 + m) * H_ + col] = acc0[r];
    xp[(size_t)(kc * 32 + 16 + m) * H_ + col] = acc1[r];
  }
}

// ---------- fused W_ih / W_hh GEMM with inline x / hprev construction ----------
__global__ __launch_bounds__(256) void ihhh_gemm(
    const float* __restrict__ xp, const float* __restrict__ b_c,
    const float* __restrict__ hidden,
    const float* __restrict__ W_ih, const float* __restrict__ W_hh,
    float* __restrict__ gip, float* __restrict__ ghp) {
  int nb = blockIdx.x, kc = blockIdx.y, z = blockIdx.z, tid = threadIdx.x;
  __shared__ unsigned short A_lds[32][136];
  {
    int b = tid >> 3, cg = tid & 7;
    int c0 = cg * 16;
    int h0 = kc * 128 + c0;
    if (z == 0) {
      #pragma unroll
      for (int c = 0; c < 16; c += 4) {
        float4 bias = *(const float4*)(b_c + h0 + c);
        float s0 = bias.x, s1 = bias.y, s2 = bias.z, s3 = bias.w;
        #pragma unroll
        for (int sc = 0; sc < 16; ++sc) {
          float4 v = *(const float4*)(xp + ((size_t)(sc * B_ + b)) * H_ + h0 + c);
          s0 += v.x; s1 += v.y; s2 += v.z; s3 += v.w;
        }
        ushort4 o;
        o.x = f2b(fmaxf(s0, 0.f)); o.y = f2b(fmaxf(s1, 0.f));
        o.z = f2b(fmaxf(s2, 0.f)); o.w = f2b(fmaxf(s3, 0.f));
        *(ushort4*)&A_lds[b][c0 + c] = o;
      }
    } else {
      #pragma unroll
      for (int c = 0; c < 16; c += 4) {
        float4 v = *(const float4*)(hidden + (size_t)b * H_ + h0 + c);
        ushort4 o; o.x = f2b(v.x); o.y = f2b(v.y); o.z = f2b(v.z); o.w = f2b(v.w);
        *(ushort4*)&A_lds[b][c0 + c] = o;
      }
    }
  }
  __syncthreads();
  const float* Bw = z ? W_hh : W_ih;
  float* C = z ? ghp : gip;
  int wave = tid >> 6, lane = tid & 63, l15 = lane & 15, l16 = lane >> 4;
  int col = nb * 64 + wave * 16 + l15;
  const float* bp = Bw + (size_t)col * 1024 + kc * 128 + l16 * 8;
  f32x4 acc0 = {0.f,0.f,0.f,0.f}, acc1 = {0.f,0.f,0.f,0.f};
  #pragma unroll
  for (int k = 0; k < 128; k += 32) {
    bf16x8 a0 = *(const bf16x8*)&A_lds[l15][k + l16 * 8];
    bf16x8 a1 = *(const bf16x8*)&A_lds[16 + l15][k + l16 * 8];
    float4 bv0 = *(const float4*)(bp + k);
    float4 bv1 = *(const float4*)(bp + k + 4);
    bf16x8 bb;
    bb[0] = (short)f2b(bv0.x); bb[1] = (short)f2b(bv0.y);
    bb[2] = (short)f2b(bv0.z); bb[3] = (short)f2b(bv0.w);
    bb[4] = (short)f2b(bv1.x); bb[5] = (short)f2b(bv1.y);
    bb[6] = (short)f2b(bv1.z); bb[7] = (short)f2b(bv1.w);
    acc0 = __builtin_amdgcn_mfma_f32_16x16x32_bf16(a0, bb, acc0, 0, 0, 0);
    acc1 = __builtin_amdgcn_mfma_f32_16x16x32_bf16(a1, bb, acc1, 0, 0, 0);
  }
  #pragma unroll
  for (int r = 0; r < 4; ++r) {
    int m = l16 * 4 + r;
    C[(size_t)(kc * 32 + m) * 3072 + col] = acc0[r];
    C[(size_t)(kc * 32 + 16 + m) * 3072 + col] = acc1[r];
  }
}

// ---------- GRU gates + h_new (8 chunks) ----------
__global__ void gates_kernel(const float* __restrict__ gip, const float* __restrict__ ghp,
                             const float* __restrict__ b_ih, const float* __restrict__ b_hh,
                             const float* __restrict__ hidden, float* __restrict__ hnew_out,
                             unsigned short* __restrict__ hr_bf) {
  int i = blockIdx.x * 256 + threadIdx.x;   // 32768
  int b = i >> 10, h = i & 1023;
  float g[6];
  #pragma unroll
  for (int t = 0; t < 3; ++t) {
    int j = h + t * H_;
    float vi = b_ih[j], vh = b_hh[j];
    #pragma unroll
    for (int kc = 0; kc < 8; ++kc) {
      vi += gip[(size_t)(kc * B_ + b) * 3072 + j];
      vh += ghp[(size_t)(kc * B_ + b) * 3072 + j];
    }
    g[t] = vi; g[3 + t] = vh;
  }
  float r = 1.f / (1.f + expf(-(g[0] + g[3])));
  float z = 1.f / (1.f + expf(-(g[1] + g[4])));
  float n = tanhf(g[2] + r * g[5]);
  float hv = (1.f - z) * n + z * hidden[i];
  hnew_out[i] = hv;
  hr_bf[i] = f2b(hv > 0.f ? hv : 0.f);
}

// ---------- final skinny GEMM: out[32,V] = hr_bf @ W_fc^T + b_fc ----------
__global__ __launch_bounds__(256) void fc_gemm(
    const unsigned short* __restrict__ A, const float* __restrict__ Bw,
    float* __restrict__ C, const float* __restrict__ bias) {
  const int N = V_, K = 1024;
  int n0 = blockIdx.x * 64;
  int wave = threadIdx.x >> 6, lane = threadIdx.x & 63;
  int l15 = lane & 15, l16 = lane >> 4;
  int col = n0 + wave * 16 + l15;
  int vclamp = col < N ? col : N - 1;
  const unsigned short* a0p = A + l15 * K + l16 * 8;
  const unsigned short* a1p = A + (16 + l15) * K + l16 * 8;
  const float* bp = Bw + (size_t)vclamp * K + l16 * 8;
  f32x4 acc0 = {0.f,0.f,0.f,0.f}, acc1 = {0.f,0.f,0.f,0.f};
  #pragma unroll 4
  for (int k = 0; k < K; k += 32) {
    bf16x8 a0 = *(const bf16x8*)(a0p + k);
    bf16x8 a1 = *(const bf16x8*)(a1p + k);
    float4 bv0 = *(const float4*)(bp + k);
    float4 bv1 = *(const float4*)(bp + k + 4);
    bf16x8 bb;
    bb[0] = (short)f2b(bv0.x); bb[1] = (short)f2b(bv0.y);
    bb[2] = (short)f2b(bv0.z); bb[3] = (short)f2b(bv0.w);
    bb[4] = (short)f2b(bv1.x); bb[5] = (short)f2b(bv1.y);
    bb[6] = (short)f2b(bv1.z); bb[7] = (short)f2b(bv1.w);
    acc0 = __builtin_amdgcn_mfma_f32_16x16x32_bf16(a0, bb, acc0, 0, 0, 0);
    acc1 = __builtin_amdgcn_mfma_f32_16x16x32_bf16(a1, bb, acc1, 0, 0, 0);
  }
  if (col < N) {
    float bv = bias[col];
    #pragma unroll
    for (int r = 0; r < 4; ++r) {
      int m = l16 * 4 + r;
      C[(size_t)m * N + col] = acc0[r] + bv;
      C[(size_t)(16 + m) * N + col] = acc1[r] + bv;
    }
  }
}

extern "C" void kernel_launch(void* const* d_in, const int* in_sizes, int n_in,
                              void* d_out, int out_size, void* d_ws, size_t ws_size,
                              hipStream_t stream) {
  const int*   word   = (const int*)  d_in[0];
  const float* hidden = (const float*)d_in[1];
  const float* enc    = (const float*)d_in[2];
  const float* emb    = (const float*)d_in[3];
  const float* W_a1   = (const float*)d_in[4];
  const float* b_a1   = (const float*)d_in[5];
  const float* W_a2   = (const float*)d_in[6];
  const float* b_c    = (const float*)d_in[9];
  const float* W_c    = (const float*)d_in[8];
  const float* W_ih   = (const float*)d_in[10];
  const float* W_hh   = (const float*)d_in[11];
  const float* b_ih   = (const float*)d_in[12];
  const float* b_hh   = (const float*)d_in[13];
  const float* W_fc   = (const float*)d_in[14];
  const float* b_fc   = (const float*)d_in[15];
  float* out = (float*)d_out;

  if (ws_size < 73596928ull) return;  // loud failure

  char* ws = (char*)d_ws;
  unsigned short* enc_bf   = (unsigned short*)(ws + 0);
  float*          gip      = (float*)         (ws + 0);
  float*          ghp      = (float*)         (ws + 3145728);
  unsigned short* wa1_bf   = (unsigned short*)(ws + 67108864);
  float*          xp       = (float*)         (ws + 67108864);
  float*          part2    = (float*)         (ws + 69206016);
  float*          partials = (float*)         (ws + 69337088);
  float*          ctxp     = (float*)         (ws + 71434240);
  unsigned short* hr_bf    = (unsigned short*)(ws + 73531392);

  hipFuncSetAttribute((const void*)scores_gemm8,
                      hipFuncAttributeMaxDynamicSharedMemorySize, 131072);

  prologue_kernel<<<dim3(17408), dim3(256), 0, stream>>>(enc, enc_bf, W_a1, hidden, b_a1,
                                                         wa1_bf, part2);
  scores_gemm8<<<dim3(128, 4), dim3(512), 131072, stream>>>(enc_bf, wa1_bf, part2, W_a2, partials);
  smctx_kernel<<<dim3(16, 32), dim3(256), 0, stream>>>(partials, enc_bf, ctxp);
  wc_gemm<<<dim3(16, 16), dim3(256), 0, stream>>>(word, emb, ctxp, W_c, xp);
  ihhh_gemm<<<dim3(48, 8, 2), dim3(256), 0, stream>>>(xp, b_c, hidden, W_ih, W_hh, gip, ghp);
  gates_kernel<<<dim3(128), dim3(256), 0, stream>>>(gip, ghp, b_ih, b_hh, hidden,
                                                    out + (size_t)B_ * V_, hr_bf);
  fc_gemm<<<dim3(786), dim3(256), 0, stream>>>(hr_bf, W_fc, out, b_fc);
}